// Round 7
// baseline (566.382 us; speedup 1.0000x reference)
//
#include <hip/hip_runtime.h>
#include <hip/hip_cooperative_groups.h>
namespace cg = cooperative_groups;

#define NREAL 20000
#define MPAD  20096      // 314 * 64
#define HDIM  256
#define ODIM  128
#define NEDGE 320000
#define NCH   79         // ceil(NREAL/256)
#define CSR_GRID 512

typedef __attribute__((ext_vector_type(4))) float f32x4;
typedef __attribute__((ext_vector_type(8))) short s16x8;
typedef __attribute__((ext_vector_type(4))) unsigned short u16x4;
typedef unsigned short u16;
typedef unsigned long long u64;

__device__ inline u16 f2bf(float f) {
    unsigned int u = __float_as_uint(f);
    return (u16)((u + 0x7FFFu + ((u >> 16) & 1u)) >> 16);
}
__device__ inline float bf2f(u16 s) { return __uint_as_float(((unsigned)s) << 16); }

__device__ __forceinline__ void gload16(const void* g, void* l) {
    __builtin_amdgcn_global_load_lds((const __attribute__((address_space(1))) void*)g,
                                     (__attribute__((address_space(3))) void*)l, 16, 0, 0);
}

// ---------------- fused CSR build + prep (cooperative, grid-synced phases) ----------------
__global__ __launch_bounds__(256) void k_csr(
    const int* __restrict__ src, const int* __restrict__ dst,
    const float* __restrict__ attr, const float* __restrict__ x,
    const float* __restrict__ wrel, const float* __restrict__ wroot,
    const float* __restrict__ wout,
    int* __restrict__ deg, int* __restrict__ rowptr, int* __restrict__ cursor,
    int* __restrict__ bsum, u64* __restrict__ csr_edge,
    u16* __restrict__ hbf, u16* __restrict__ brelT, u16* __restrict__ brootT,
    u16* __restrict__ boutT)
{
    cg::grid_group grid = cg::this_grid();
    __shared__ int sm[256];
    const int nb = gridDim.x, b = blockIdx.x, t = threadIdx.x;
    const int gt = b * 256 + t, gsz = nb * 256;

    // phase 0: zero deg + pad-convert x + weight transpose/convert
    for (int i = gt; i < NREAL; i += gsz) deg[i] = 0;
    for (long gid = gt; gid < (long)MPAD * HDIM / 4; gid += gsz) {
        long base = gid * 4;
        long row = base >> 8;
        f32x4 v = {0.f, 0.f, 0.f, 0.f};
        if (row < NREAL) v = *(const f32x4*)(x + base);
        u16x4 hv;
        for (int j = 0; j < 4; ++j) hv[j] = f2bf(v[j]);
        *(u16x4*)(hbf + base) = hv;
    }
    for (int i = gt; i < 3 * 65536; i += gsz) {
        int l = i >> 16, r = i & 65535, n = r >> 8, k = r & 255;
        brelT[i]  = f2bf(wrel [l * 65536 + k * 256 + n]);
        brootT[i] = f2bf(wroot[l * 65536 + k * 256 + n]);
    }
    for (int i = gt; i < 128 * 256; i += gsz) {
        int n = i >> 8, k = i & 255;
        boutT[i] = f2bf(wout[k * 128 + n]);
    }
    grid.sync();

    // phase 1: degree count
    for (int e = gt; e < NEDGE; e += gsz) atomicAdd(&deg[dst[e]], 1);
    grid.sync();

    // phase 2a: per-chunk (256) sums
    for (int c = b; c < NCH; c += nb) {
        int i = c * 256 + t;
        sm[t] = (i < NREAL) ? deg[i] : 0;
        __syncthreads();
        for (int off = 128; off; off >>= 1) {
            if (t < off) sm[t] += sm[t + off];
            __syncthreads();
        }
        if (t == 0) bsum[c] = sm[0];
        __syncthreads();
    }
    grid.sync();

    // phase 2b: block 0 exclusive-scans the chunk sums
    if (b == 0) {
        int v = (t < NCH) ? bsum[t] : 0;
        sm[t] = v;
        __syncthreads();
        for (int off = 1; off < 256; off <<= 1) {
            int u = (t >= off) ? sm[t - off] : 0;
            __syncthreads();
            sm[t] += u;
            __syncthreads();
        }
        if (t < NCH) bsum[t] = sm[t] - v;   // exclusive chunk offsets
    }
    grid.sync();

    // phase 2c: per-chunk scan -> rowptr / cursor
    for (int c = b; c < NCH; c += nb) {
        int i = c * 256 + t;
        int v = (i < NREAL) ? deg[i] : 0;
        sm[t] = v;
        __syncthreads();
        for (int off = 1; off < 256; off <<= 1) {
            int u = (t >= off) ? sm[t - off] : 0;
            __syncthreads();
            sm[t] += u;
            __syncthreads();
        }
        if (i < NREAL) {
            int excl = bsum[c] + sm[t] - v;
            rowptr[i] = excl;
            cursor[i] = excl;
        }
        __syncthreads();
    }
    if (gt == 0) rowptr[NREAL] = NEDGE;
    grid.sync();

    // phase 3: fill (atomic cursor scatter)
    for (int e = gt; e < NEDGE; e += gsz) {
        int d = dst[e];
        int p = atomicAdd(&cursor[d], 1);
        csr_edge[p] = ((u64)__float_as_uint(attr[e]) << 32) | (unsigned)src[e];
    }
    grid.sync();

    // phase 4: canonical segment sort (determinism), wave per node
    const int lane = t & 63;
    for (int node = b * 4 + (t >> 6); node < NREAL; node += nb * 4) {
        const int beg = rowptr[node], end = rowptr[node + 1];
        const int m = end - beg;
        if (m <= 1) continue;
        if (m <= 64) {
            u64 val = (lane < m) ? csr_edge[beg + lane] : ~0ull;
            #pragma unroll
            for (int ph = 0; ph < 64; ++ph) {
                int base = ph & 1;
                int partner = lane + (((lane ^ base) & 1) ? -1 : +1);
                if (partner < 0 || partner > 63) partner = lane;
                u64 p = __shfl(val, partner);
                if (partner != lane)
                    val = (lane < partner) ? (val < p ? val : p) : (val > p ? val : p);
            }
            if (lane < m) csr_edge[beg + lane] = val;
        } else if (lane == 0) {
            for (int i = beg + 1; i < end; ++i) {
                u64 key = csr_edge[i];
                int j = i - 1;
                while (j >= beg && csr_edge[j] > key) { csr_edge[j + 1] = csr_edge[j]; --j; }
                csr_edge[j + 1] = key;
            }
        }
    }
}

// ---------------- aggregation: wave per node, 2 edges/iter, bf16 gather ----------------
__global__ __launch_bounds__(256) void k_aggregate(
    const u16* __restrict__ hbf, const int* __restrict__ rowptr,
    const u64* __restrict__ csr_edge, u16* __restrict__ agg)
{
    const int node = blockIdx.x * 4 + (threadIdx.x >> 6);
    const int lane = threadIdx.x & 63;
    const int half = lane >> 5;
    const int col8 = (lane & 31) * 8;
    float acc[8] = {0.f,0.f,0.f,0.f,0.f,0.f,0.f,0.f};
    if (node < NREAL) {
        const int beg = rowptr[node], end = rowptr[node + 1];
        for (int c = beg; c < end; c += 64) {
            int m = end - c; if (m > 64) m = 64;
            u64 ej = csr_edge[c + (lane < m ? lane : 0)];
            int   sj = (int)(unsigned)ej;
            float aj = (lane < m) ? __uint_as_float((unsigned)(ej >> 32)) : 0.f;
            int npair = (m + 1) >> 1;
            #pragma unroll 4
            for (int p = 0; p < npair; ++p) {
                int sel = 2 * p + half;
                int   s = __shfl(sj, sel);
                float a = __shfl(aj, sel);
                s16x8 v = *(const s16x8*)(hbf + (long)s * HDIM + col8);
                #pragma unroll
                for (int q = 0; q < 8; ++q)
                    acc[q] += a * bf2f((u16)v[q]);
            }
        }
    }
    #pragma unroll
    for (int q = 0; q < 8; ++q)
        acc[q] += __shfl_xor(acc[q], 32);
    if (half == 0) {
        s16x8 hv;
        #pragma unroll
        for (int q = 0; q < 8; ++q) hv[q] = (short)f2bf(acc[q]);
        *(s16x8*)(agg + (long)node * HDIM + col8) = hv;
    }
}

// ---------------- GEMM: 64x128 tile, gload_lds staging, swizzled LDS ----------------
// A bf16 [MPAD][256]; B pre-transposed bf16 [Nt][256]. BK=32.
// LDS u16 index: row*32 + (lk ^ (((row>>1)&3)<<3)); staged via pre-swizzled
// global source so gload_lds's linear (base + lane*16B) write lands swizzled.
__global__ __launch_bounds__(256) void k_gemm(
    const u16* __restrict__ A1, const u16* __restrict__ A2,
    const u16* __restrict__ BT1, const u16* __restrict__ BT2,
    const float* __restrict__ bias,
    u16* __restrict__ hout, float* __restrict__ final_out, int Nt)
{
    __shared__ __align__(16) u16 As[64 * 32];
    __shared__ __align__(16) u16 Bs[128 * 32];

    const int t    = threadIdx.x;
    const int bm   = blockIdx.x, bn = blockIdx.y;
    const int lane = t & 63;
    const int wave = t >> 6;
    const int wr   = (wave >> 1) * 32;   // 0 | 32
    const int wc   = (wave & 1) * 64;    // 0 | 64
    const int lrow = lane & 15;
    const int lk   = (lane >> 4) * 8;

    f32x4 acc[2][4];
    #pragma unroll
    for (int i = 0; i < 2; ++i)
        #pragma unroll
        for (int j = 0; j < 4; ++j)
            #pragma unroll
            for (int r = 0; r < 4; ++r) acc[i][j][r] = 0.f;

    // staging: lane covers row chunk*16 + (lane>>2), 16B slot (lane&3), src slot swizzled
    const int arow  = wave * 16 + (lane >> 2);   // A row (64 rows = 4 wave-chunks)
    const int brow0 = wave * 32 + (lane >> 2);   // B rows (+16*i, 128 rows = 8 chunks)
    const int slot  = lane & 3;

    const int nmat = A2 ? 2 : 1;
    for (int mat = 0; mat < nmat; ++mat) {
        const u16* A_g = mat ? A2  : A1;
        const u16* B_g = mat ? BT2 : BT1;
        #pragma unroll 2
        for (int k0 = 0; k0 < HDIM; k0 += 32) {
            __syncthreads();
            {
                int ssA = (slot ^ ((arow >> 1) & 3)) * 8;
                gload16(A_g + (size_t)(bm * 64 + arow) * HDIM + k0 + ssA, &As[wave * 512]);
                #pragma unroll
                for (int i = 0; i < 2; ++i) {
                    int brow = brow0 + i * 16;
                    int ssB  = (slot ^ ((brow >> 1) & 3)) * 8;
                    gload16(B_g + (size_t)(bn * 128 + brow) * HDIM + k0 + ssB,
                            &Bs[(wave * 2 + i) * 512]);
                }
            }
            __syncthreads();
            s16x8 bfr[4];
            #pragma unroll
            for (int nj = 0; nj < 4; ++nj) {
                int r = wc + nj * 16 + lrow;
                bfr[nj] = *(const s16x8*)&Bs[r * 32 + (lk ^ (((r >> 1) & 3) << 3))];
            }
            #pragma unroll
            for (int mi = 0; mi < 2; ++mi) {
                int r = wr + mi * 16 + lrow;
                s16x8 a = *(const s16x8*)&As[r * 32 + (lk ^ (((r >> 1) & 3) << 3))];
                #pragma unroll
                for (int nj = 0; nj < 4; ++nj)
                    acc[mi][nj] = __builtin_amdgcn_mfma_f32_16x16x32_bf16(a, bfr[nj], acc[mi][nj], 0, 0, 0);
            }
        }
    }

    // epilogue: bias + relu
    const int rb = (lane >> 4) * 4;
    #pragma unroll
    for (int mi = 0; mi < 2; ++mi) {
        #pragma unroll
        for (int nj = 0; nj < 4; ++nj) {
            int col = bn * 128 + wc + nj * 16 + lrow;
            float bsv = bias[col];
            #pragma unroll
            for (int r = 0; r < 4; ++r) {
                int row = bm * 64 + wr + mi * 16 + rb + r;
                float v = acc[mi][nj][r] + bsv;
                v = v > 0.f ? v : 0.f;
                if (final_out) {
                    if (row < NREAL) final_out[(long)row * Nt + col] = v;
                } else {
                    hout[(long)row * HDIM + col] = f2bf(v);
                }
            }
        }
    }
}

static inline char* align256(char* p) {
    return (char*)(((size_t)p + 255) & ~(size_t)255);
}

extern "C" void kernel_launch(void* const* d_in, const int* in_sizes, int n_in,
                              void* d_out, int out_size, void* d_ws, size_t ws_size,
                              hipStream_t stream) {
    const float* x     = (const float*)d_in[0];
    const int*   eidx  = (const int*)  d_in[1];
    const float* attr  = (const float*)d_in[2];
    const float* wrel  = (const float*)d_in[3];
    const float* brel  = (const float*)d_in[4];
    const float* wroot = (const float*)d_in[5];
    const float* wout  = (const float*)d_in[6];
    const float* bout  = (const float*)d_in[7];
    const int* src = eidx;
    const int* dst = eidx + NEDGE;

    char* ws = (char*)d_ws;
    u16* hbfA  = (u16*)ws;        ws = align256(ws + (size_t)MPAD * HDIM * 2);
    u16* hbfB  = (u16*)ws;        ws = align256(ws + (size_t)MPAD * HDIM * 2);
    u16* aggbf = (u16*)ws;        ws = align256(ws + (size_t)MPAD * HDIM * 2);
    u16* brelT  = (u16*)ws;       ws = align256(ws + (size_t)3 * 65536 * 2);
    u16* brootT = (u16*)ws;       ws = align256(ws + (size_t)3 * 65536 * 2);
    u16* boutT  = (u16*)ws;       ws = align256(ws + (size_t)128 * 256 * 2);
    int* deg    = (int*)ws;       ws = align256(ws + (size_t)NREAL * 4);
    int* rowptr = (int*)ws;       ws = align256(ws + (size_t)(NREAL + 1) * 4);
    int* cursor = (int*)ws;       ws = align256(ws + (size_t)NREAL * 4);
    int* bsum   = (int*)ws;       ws = align256(ws + (size_t)NCH * 4);
    u64* csr_edge = (u64*)ws;     ws = align256(ws + (size_t)NEDGE * 8);

    void* args[] = {
        (void*)&src, (void*)&dst, (void*)&attr, (void*)&x,
        (void*)&wrel, (void*)&wroot, (void*)&wout,
        (void*)&deg, (void*)&rowptr, (void*)&cursor, (void*)&bsum,
        (void*)&csr_edge, (void*)&hbfA, (void*)&brelT, (void*)&brootT, (void*)&boutT
    };
    hipLaunchCooperativeKernel((void*)k_csr, dim3(CSR_GRID), dim3(256), args, 0, stream);

    u16* h_c = hbfA;
    u16* h_n = hbfB;
    for (int l = 0; l < 3; ++l) {
        k_aggregate<<<MPAD / 4, 256, 0, stream>>>(h_c, rowptr, csr_edge, aggbf);
        k_gemm<<<dim3(MPAD / 64, 2), 256, 0, stream>>>(
            aggbf, h_c,
            brelT + (size_t)l * 65536, brootT + (size_t)l * 65536,
            brel + (size_t)l * HDIM,
            h_n, nullptr, HDIM);
        u16* tp = h_c; h_c = h_n; h_n = tp;
    }
    k_gemm<<<dim3(MPAD / 64, 1), 256, 0, stream>>>(
        h_c, nullptr, boutT, nullptr, bout,
        nullptr, (float*)d_out, ODIM);
}

// Round 8
// 252.992 us; speedup vs baseline: 2.2387x; 2.2387x over previous
//
#include <hip/hip_runtime.h>

#define NREAL 20000
#define MPAD  20096      // 314 * 64
#define HDIM  256
#define ODIM  128
#define NEDGE 320000
#define SCAN_B 20        // ceil(NREAL/1024)

typedef __attribute__((ext_vector_type(4))) float f32x4;
typedef __attribute__((ext_vector_type(8))) short s16x8;
typedef __attribute__((ext_vector_type(4))) unsigned short u16x4;
typedef unsigned short u16;
typedef unsigned long long u64;

__device__ inline u16 f2bf(float f) {
    unsigned int u = __float_as_uint(f);
    return (u16)((u + 0x7FFFu + ((u >> 16) & 1u)) >> 16);
}
__device__ inline float bf2f(u16 s) { return __uint_as_float(((unsigned)s) << 16); }

__device__ __forceinline__ void gload16(const void* g, void* l) {
    __builtin_amdgcn_global_load_lds((const __attribute__((address_space(1))) void*)g,
                                     (__attribute__((address_space(3))) void*)l, 16, 0, 0);
}

// ---------------- prep: pad-convert x, weight transpose/convert, degree count ----------------
// (independent grid-stride phases; deg zeroed by preceding memset dispatch)
__global__ __launch_bounds__(256) void k_prep(
    const float* __restrict__ x, u16* __restrict__ hbf,
    const float* __restrict__ wrel, const float* __restrict__ wroot,
    const float* __restrict__ wout,
    u16* __restrict__ brelT, u16* __restrict__ brootT, u16* __restrict__ boutT,
    const int* __restrict__ dst, int* __restrict__ deg)
{
    const int gt = blockIdx.x * 256 + threadIdx.x;
    const int gsz = gridDim.x * 256;
    for (long gid = gt; gid < (long)MPAD * HDIM / 4; gid += gsz) {
        long base = gid * 4;
        long row  = base >> 8;
        f32x4 v = {0.f, 0.f, 0.f, 0.f};
        if (row < NREAL) v = *(const f32x4*)(x + base);
        u16x4 hv;
        for (int j = 0; j < 4; ++j) hv[j] = f2bf(v[j]);
        *(u16x4*)(hbf + base) = hv;
    }
    for (int i = gt; i < 3 * 65536; i += gsz) {
        int l = i >> 16, r = i & 65535, n = r >> 8, k = r & 255;
        brelT[i]  = f2bf(wrel [l * 65536 + k * 256 + n]);
        brootT[i] = f2bf(wroot[l * 65536 + k * 256 + n]);
    }
    for (int i = gt; i < 128 * 256; i += gsz) {
        int n = i >> 8, k = i & 255;
        boutT[i] = f2bf(wout[k * 128 + n]);
    }
    for (int e = gt; e < NEDGE; e += gsz) atomicAdd(&deg[dst[e]], 1);
}

// ---------------- scan chain ----------------
__global__ __launch_bounds__(1024) void k_blocksum(const int* __restrict__ deg,
                                                   int* __restrict__ bsum) {
    __shared__ int red[16];
    int b = blockIdx.x, t = threadIdx.x;
    int i = b * 1024 + t;
    int v = (i < NREAL) ? deg[i] : 0;
    for (int off = 32; off; off >>= 1) v += __shfl_down(v, off);
    if ((t & 63) == 0) red[t >> 6] = v;
    __syncthreads();
    if (t < 16) {
        int s = red[t];
        for (int off = 8; off; off >>= 1) s += __shfl_down(s, off);
        if (t == 0) bsum[b] = s;
    }
}

__global__ void k_scansmall(const int* __restrict__ bsum, int* __restrict__ boff) {
    int t = threadIdx.x;  // one wave
    int v = (t < SCAN_B) ? bsum[t] : 0;
    int orig = v;
    for (int off = 1; off < 64; off <<= 1) {
        int u = __shfl_up(v, off);
        if (t >= off) v += u;
    }
    if (t < SCAN_B) boff[t] = v - orig;
}

__global__ __launch_bounds__(1024) void k_scanfinal(const int* __restrict__ deg,
                                                    const int* __restrict__ boff,
                                                    int* __restrict__ rowptr,
                                                    int* __restrict__ cursor) {
    __shared__ int sm[1024];
    int b = blockIdx.x, t = threadIdx.x;
    int i = b * 1024 + t;
    int v = (i < NREAL) ? deg[i] : 0;
    sm[t] = v;
    __syncthreads();
    for (int off = 1; off < 1024; off <<= 1) {
        int u = (t >= off) ? sm[t - off] : 0;
        __syncthreads();
        if (t >= off) sm[t] += u;
        __syncthreads();
    }
    if (i < NREAL) {
        int excl = boff[b] + sm[t] - v;
        rowptr[i] = excl;
        cursor[i] = excl;
    }
    if (b == 0 && t == 0) rowptr[NREAL] = NEDGE;
}

__global__ void k_fill(const int* __restrict__ src, const int* __restrict__ dst,
                       const float* __restrict__ attr, int* __restrict__ cursor,
                       u64* __restrict__ csr_edge) {
    int e = blockIdx.x * 256 + threadIdx.x;
    if (e < NEDGE) {
        int d = dst[e];
        int p = atomicAdd(&cursor[d], 1);
        csr_edge[p] = ((u64)__float_as_uint(attr[e]) << 32) | (unsigned)src[e];
    }
}

// ---------------- canonical segment sort (determinism) ----------------
__global__ __launch_bounds__(256) void k_sortseg(const int* __restrict__ rowptr,
                                                 u64* __restrict__ csr_edge) {
    const int node = blockIdx.x * 4 + (threadIdx.x >> 6);
    const int lane = threadIdx.x & 63;
    if (node >= NREAL) return;
    const int beg = rowptr[node], end = rowptr[node + 1];
    const int m = end - beg;
    if (m <= 1) return;
    if (m <= 64) {
        u64 val = (lane < m) ? csr_edge[beg + lane] : ~0ull;
        #pragma unroll
        for (int ph = 0; ph < 64; ++ph) {
            int base = ph & 1;
            int partner = lane + (((lane ^ base) & 1) ? -1 : +1);
            if (partner < 0 || partner > 63) partner = lane;
            u64 p = __shfl(val, partner);
            if (partner != lane)
                val = (lane < partner) ? (val < p ? val : p) : (val > p ? val : p);
        }
        if (lane < m) csr_edge[beg + lane] = val;
    } else if (lane == 0) {
        for (int i = beg + 1; i < end; ++i) {
            u64 key = csr_edge[i];
            int j = i - 1;
            while (j >= beg && csr_edge[j] > key) { csr_edge[j + 1] = csr_edge[j]; --j; }
            csr_edge[j + 1] = key;
        }
    }
}

// ---------------- aggregation: column-split (4 groups of 64 cols), XCD-pinned ----------------
// Each group's table slice = 128 B/row * 20000 = 2.56 MB -> resident in the
// owning XCD's 4 MB L2. Edge meta streams via nontemporal loads (no L2 pollution).
// Wave per node; 8 edges/iter (lane = eslot*8 + cpart, 16 B per lane).
__global__ __launch_bounds__(256) void k_aggregate(
    const u16* __restrict__ hbf, const int* __restrict__ rowptr,
    const u64* __restrict__ csr_edge, u16* __restrict__ agg)
{
    const int bid = blockIdx.x;
    const int r = bid & 7;                       // XCD (heuristic: round-robin)
    const int group = r >> 1;                    // XCD pair -> column group
    const int nodeblk = (bid >> 3) * 2 + (r & 1);  // [0, 5000)
    const int node = nodeblk * 4 + (threadIdx.x >> 6);
    const int lane = threadIdx.x & 63;
    const int eslot = lane >> 3;                 // 0..7
    const int cpart = lane & 7;                  // 0..7
    const int colbase = group * 64 + cpart * 8;

    float acc[8] = {0.f,0.f,0.f,0.f,0.f,0.f,0.f,0.f};
    if (node < NREAL) {
        const int beg = rowptr[node], end = rowptr[node + 1];
        for (int c = beg; c < end; c += 64) {
            int m = end - c; if (m > 64) m = 64;
            u64 ej = __builtin_nontemporal_load(csr_edge + c + (lane < m ? lane : 0));
            int   sj = (int)(unsigned)ej;
            float aj = (lane < m) ? __uint_as_float((unsigned)(ej >> 32)) : 0.f;
            int nit = (m + 7) >> 3;
            #pragma unroll 2
            for (int it = 0; it < nit; ++it) {
                int sel = it * 8 + eslot;        // aj==0 on slots >= m
                int   s = __shfl(sj, sel);
                float a = __shfl(aj, sel);
                s16x8 v = *(const s16x8*)(hbf + (long)s * HDIM + colbase);
                #pragma unroll
                for (int q = 0; q < 8; ++q)
                    acc[q] += a * bf2f((u16)v[q]);
            }
        }
    }
    #pragma unroll
    for (int q = 0; q < 8; ++q) {
        acc[q] += __shfl_xor(acc[q], 8);
        acc[q] += __shfl_xor(acc[q], 16);
        acc[q] += __shfl_xor(acc[q], 32);
    }
    if (eslot == 0 && node < NREAL) {
        s16x8 hv;
        #pragma unroll
        for (int q = 0; q < 8; ++q) hv[q] = (short)f2bf(acc[q]);
        *(s16x8*)(agg + (long)node * HDIM + colbase) = hv;
    }
}

// ---------------- zero pad rows of agg (once; pads never rewritten) ----------------
__global__ void k_padzero(u16* __restrict__ agg) {
    long i = (long)blockIdx.x * 256 + threadIdx.x;           // over pad elems /8
    long base = (long)NREAL * HDIM + i * 8;
    if (base < (long)MPAD * HDIM) {
        s16x8 z = {0,0,0,0,0,0,0,0};
        *(s16x8*)(agg + base) = z;
    }
}

// ---------------- GEMM: 64x128 tile, gload_lds staging, swizzled LDS ----------------
__global__ __launch_bounds__(256) void k_gemm(
    const u16* __restrict__ A1, const u16* __restrict__ A2,
    const u16* __restrict__ BT1, const u16* __restrict__ BT2,
    const float* __restrict__ bias,
    u16* __restrict__ hout, float* __restrict__ final_out, int Nt)
{
    __shared__ __align__(16) u16 As[64 * 32];
    __shared__ __align__(16) u16 Bs[128 * 32];

    const int t    = threadIdx.x;
    const int bm   = blockIdx.x, bn = blockIdx.y;
    const int lane = t & 63;
    const int wave = t >> 6;
    const int wr   = (wave >> 1) * 32;   // 0 | 32
    const int wc   = (wave & 1) * 64;    // 0 | 64
    const int lrow = lane & 15;
    const int lk   = (lane >> 4) * 8;

    f32x4 acc[2][4];
    #pragma unroll
    for (int i = 0; i < 2; ++i)
        #pragma unroll
        for (int j = 0; j < 4; ++j)
            #pragma unroll
            for (int r = 0; r < 4; ++r) acc[i][j][r] = 0.f;

    const int arow  = wave * 16 + (lane >> 2);
    const int brow0 = wave * 32 + (lane >> 2);
    const int slot  = lane & 3;

    const int nmat = A2 ? 2 : 1;
    for (int mat = 0; mat < nmat; ++mat) {
        const u16* A_g = mat ? A2  : A1;
        const u16* B_g = mat ? BT2 : BT1;
        #pragma unroll 2
        for (int k0 = 0; k0 < HDIM; k0 += 32) {
            __syncthreads();
            {
                int ssA = (slot ^ ((arow >> 1) & 3)) * 8;
                gload16(A_g + (size_t)(bm * 64 + arow) * HDIM + k0 + ssA, &As[wave * 512]);
                #pragma unroll
                for (int i = 0; i < 2; ++i) {
                    int brow = brow0 + i * 16;
                    int ssB  = (slot ^ ((brow >> 1) & 3)) * 8;
                    gload16(B_g + (size_t)(bn * 128 + brow) * HDIM + k0 + ssB,
                            &Bs[(wave * 2 + i) * 512]);
                }
            }
            __syncthreads();
            s16x8 bfr[4];
            #pragma unroll
            for (int nj = 0; nj < 4; ++nj) {
                int rr = wc + nj * 16 + lrow;
                bfr[nj] = *(const s16x8*)&Bs[rr * 32 + (lk ^ (((rr >> 1) & 3) << 3))];
            }
            #pragma unroll
            for (int mi = 0; mi < 2; ++mi) {
                int rr = wr + mi * 16 + lrow;
                s16x8 a = *(const s16x8*)&As[rr * 32 + (lk ^ (((rr >> 1) & 3) << 3))];
                #pragma unroll
                for (int nj = 0; nj < 4; ++nj)
                    acc[mi][nj] = __builtin_amdgcn_mfma_f32_16x16x32_bf16(a, bfr[nj], acc[mi][nj], 0, 0, 0);
            }
        }
    }

    const int rb = (lane >> 4) * 4;
    #pragma unroll
    for (int mi = 0; mi < 2; ++mi) {
        #pragma unroll
        for (int nj = 0; nj < 4; ++nj) {
            int col = bn * 128 + wc + nj * 16 + lrow;
            float bsv = bias[col];
            #pragma unroll
            for (int r = 0; r < 4; ++r) {
                int row = bm * 64 + wr + mi * 16 + rb + r;
                float v = acc[mi][nj][r] + bsv;
                v = v > 0.f ? v : 0.f;
                if (final_out) {
                    if (row < NREAL) final_out[(long)row * Nt + col] = v;
                } else {
                    hout[(long)row * HDIM + col] = f2bf(v);
                }
            }
        }
    }
}

static inline char* align256(char* p) {
    return (char*)(((size_t)p + 255) & ~(size_t)255);
}

extern "C" void kernel_launch(void* const* d_in, const int* in_sizes, int n_in,
                              void* d_out, int out_size, void* d_ws, size_t ws_size,
                              hipStream_t stream) {
    const float* x     = (const float*)d_in[0];
    const int*   eidx  = (const int*)  d_in[1];
    const float* attr  = (const float*)d_in[2];
    const float* wrel  = (const float*)d_in[3];
    const float* brel  = (const float*)d_in[4];
    const float* wroot = (const float*)d_in[5];
    const float* wout  = (const float*)d_in[6];
    const float* bout  = (const float*)d_in[7];
    const int* src = eidx;
    const int* dst = eidx + NEDGE;

    char* ws = (char*)d_ws;
    u16* hbfA  = (u16*)ws;        ws = align256(ws + (size_t)MPAD * HDIM * 2);
    u16* hbfB  = (u16*)ws;        ws = align256(ws + (size_t)MPAD * HDIM * 2);
    u16* aggbf = (u16*)ws;        ws = align256(ws + (size_t)MPAD * HDIM * 2);
    u16* brelT  = (u16*)ws;       ws = align256(ws + (size_t)3 * 65536 * 2);
    u16* brootT = (u16*)ws;       ws = align256(ws + (size_t)3 * 65536 * 2);
    u16* boutT  = (u16*)ws;       ws = align256(ws + (size_t)128 * 256 * 2);
    int* deg    = (int*)ws;       ws = align256(ws + (size_t)NREAL * 4);
    int* rowptr = (int*)ws;       ws = align256(ws + (size_t)(NREAL + 1) * 4);
    int* cursor = (int*)ws;       ws = align256(ws + (size_t)NREAL * 4);
    int* bsum   = (int*)ws;       ws = align256(ws + (size_t)SCAN_B * 4);
    int* boff   = (int*)ws;       ws = align256(ws + (size_t)SCAN_B * 4);
    u64* csr_edge = (u64*)ws;     ws = align256(ws + (size_t)NEDGE * 8);

    hipMemsetAsync(deg, 0, (size_t)NREAL * 4, stream);
    k_prep<<<2048, 256, 0, stream>>>(x, hbfA, wrel, wroot, wout,
                                     brelT, brootT, boutT, dst, deg);
    k_blocksum<<<SCAN_B, 1024, 0, stream>>>(deg, bsum);
    k_scansmall<<<1, 64, 0, stream>>>(bsum, boff);
    k_scanfinal<<<SCAN_B, 1024, 0, stream>>>(deg, boff, rowptr, cursor);
    k_fill<<<(NEDGE + 255) / 256, 256, 0, stream>>>(src, dst, attr, cursor, csr_edge);
    k_sortseg<<<(NREAL + 3) / 4, 256, 0, stream>>>(rowptr, csr_edge);
    k_padzero<<<((MPAD - NREAL) * HDIM / 8 + 255) / 256, 256, 0, stream>>>(aggbf);

    u16* h_c = hbfA;
    u16* h_n = hbfB;
    for (int l = 0; l < 3; ++l) {
        k_aggregate<<<20000, 256, 0, stream>>>(h_c, rowptr, csr_edge, aggbf);
        k_gemm<<<dim3(MPAD / 64, 2), 256, 0, stream>>>(
            aggbf, h_c,
            brelT + (size_t)l * 65536, brootT + (size_t)l * 65536,
            brel + (size_t)l * HDIM,
            h_n, nullptr, HDIM);
        u16* tp = h_c; h_c = h_n; h_n = tp;
    }
    k_gemm<<<dim3(MPAD / 64, 1), 256, 0, stream>>>(
        h_c, nullptr, boutT, nullptr, bout,
        nullptr, (float*)d_out, ODIM);
}

// Round 10
// 188.312 us; speedup vs baseline: 3.0077x; 1.3435x over previous
//
#include <hip/hip_runtime.h>

#define NREAL 20000
#define MPAD  20096      // 314 * 64
#define HDIM  256
#define ODIM  128
#define NEDGE 320000
#define SCAN_B 20        // ceil(NREAL/1024)

typedef __attribute__((ext_vector_type(4))) float f32x4;
typedef __attribute__((ext_vector_type(8))) short s16x8;
typedef __attribute__((ext_vector_type(4))) unsigned short u16x4;
typedef unsigned short u16;
typedef unsigned long long u64;

__device__ inline u16 f2bf(float f) {
    unsigned int u = __float_as_uint(f);
    return (u16)((u + 0x7FFFu + ((u >> 16) & 1u)) >> 16);
}
__device__ inline float bf2f(u16 s) { return __uint_as_float(((unsigned)s) << 16); }

__device__ __forceinline__ void gload16(const void* g, void* l) {
    __builtin_amdgcn_global_load_lds((const __attribute__((address_space(1))) void*)g,
                                     (__attribute__((address_space(3))) void*)l, 16, 0, 0);
}

// ---------------- prep: pad-convert x, weight transpose/convert, degree count ----------------
__global__ __launch_bounds__(256) void k_prep(
    const float* __restrict__ x, u16* __restrict__ hbf,
    const float* __restrict__ wrel, const float* __restrict__ wroot,
    const float* __restrict__ wout,
    u16* __restrict__ brelT, u16* __restrict__ brootT, u16* __restrict__ boutT,
    const int* __restrict__ dst, int* __restrict__ deg)
{
    const int gt = blockIdx.x * 256 + threadIdx.x;
    const int gsz = gridDim.x * 256;
    for (long gid = gt; gid < (long)MPAD * HDIM / 4; gid += gsz) {
        long base = gid * 4;
        long row  = base >> 8;
        f32x4 v = {0.f, 0.f, 0.f, 0.f};
        if (row < NREAL) v = *(const f32x4*)(x + base);
        u16x4 hv;
        for (int j = 0; j < 4; ++j) hv[j] = f2bf(v[j]);
        *(u16x4*)(hbf + base) = hv;
    }
    for (int i = gt; i < 3 * 65536; i += gsz) {
        int l = i >> 16, r = i & 65535, n = r >> 8, k = r & 255;
        brelT[i]  = f2bf(wrel [l * 65536 + k * 256 + n]);
        brootT[i] = f2bf(wroot[l * 65536 + k * 256 + n]);
    }
    for (int i = gt; i < 128 * 256; i += gsz) {
        int n = i >> 8, k = i & 255;
        boutT[i] = f2bf(wout[k * 128 + n]);
    }
    for (int e = gt; e < NEDGE; e += gsz) atomicAdd(&deg[dst[e]], 1);
}

// ---------------- scan chain ----------------
__global__ __launch_bounds__(1024) void k_blocksum(const int* __restrict__ deg,
                                                   int* __restrict__ bsum) {
    __shared__ int red[16];
    int b = blockIdx.x, t = threadIdx.x;
    int i = b * 1024 + t;
    int v = (i < NREAL) ? deg[i] : 0;
    for (int off = 32; off; off >>= 1) v += __shfl_down(v, off);
    if ((t & 63) == 0) red[t >> 6] = v;
    __syncthreads();
    if (t < 16) {
        int s = red[t];
        for (int off = 8; off; off >>= 1) s += __shfl_down(s, off);
        if (t == 0) bsum[b] = s;
    }
}

__global__ void k_scansmall(const int* __restrict__ bsum, int* __restrict__ boff) {
    int t = threadIdx.x;  // one wave
    int v = (t < SCAN_B) ? bsum[t] : 0;
    int orig = v;
    for (int off = 1; off < 64; off <<= 1) {
        int u = __shfl_up(v, off);
        if (t >= off) v += u;
    }
    if (t < SCAN_B) boff[t] = v - orig;
}

__global__ __launch_bounds__(1024) void k_scanfinal(const int* __restrict__ deg,
                                                    const int* __restrict__ boff,
                                                    int* __restrict__ rowptr,
                                                    int* __restrict__ cursor) {
    __shared__ int sm[1024];
    int b = blockIdx.x, t = threadIdx.x;
    int i = b * 1024 + t;
    int v = (i < NREAL) ? deg[i] : 0;
    sm[t] = v;
    __syncthreads();
    for (int off = 1; off < 1024; off <<= 1) {
        int u = (t >= off) ? sm[t - off] : 0;
        __syncthreads();
        if (t >= off) sm[t] += u;
        __syncthreads();
    }
    if (i < NREAL) {
        int excl = boff[b] + sm[t] - v;
        rowptr[i] = excl;
        cursor[i] = excl;
    }
    if (b == 0 && t == 0) rowptr[NREAL] = NEDGE;
}

__global__ void k_fill(const int* __restrict__ src, const int* __restrict__ dst,
                       const float* __restrict__ attr, int* __restrict__ cursor,
                       u64* __restrict__ csr_edge) {
    int e = blockIdx.x * 256 + threadIdx.x;
    if (e < NEDGE) {
        int d = dst[e];
        int p = atomicAdd(&cursor[d], 1);
        csr_edge[p] = ((u64)__float_as_uint(attr[e]) << 32) | (unsigned)src[e];
    }
}

// ---------------- aggregation: wave per node, 2 edges/iter, bf16 gather ----------------
// SORT=true (layer 1 only): canonically sort the segment in registers first
// (odd-even network), write back for layers 2-3, aggregate from the sorted
// registers. Makes downstream fp order deterministic regardless of k_fill's
// atomic scheduling order.
template <bool SORT>
__global__ __launch_bounds__(256) void k_aggregate(
    const u16* __restrict__ hbf, const int* __restrict__ rowptr,
    u64* __restrict__ csr_edge, u16* __restrict__ agg)
{
    const int node = blockIdx.x * 4 + (threadIdx.x >> 6);
    const int lane = threadIdx.x & 63;
    const int half = lane >> 5;
    const int col8 = (lane & 31) * 8;
    float acc[8] = {0.f,0.f,0.f,0.f,0.f,0.f,0.f,0.f};
    if (node < NREAL) {
        const int beg = rowptr[node], end = rowptr[node + 1];
        const int deg = end - beg;
        bool reg_path = false;
        int   sj = 0;
        float aj = 0.f;
        if (SORT) {
            if (deg >= 1 && deg <= 64) {
                u64 val = (lane < deg) ? csr_edge[beg + lane] : ~0ull;
                if (deg > 1) {
                    #pragma unroll
                    for (int ph = 0; ph < 64; ++ph) {
                        int base = ph & 1;
                        int partner = lane + (((lane ^ base) & 1) ? -1 : +1);
                        if (partner < 0 || partner > 63) partner = lane;
                        u64 p = __shfl(val, partner);
                        if (partner != lane)
                            val = (lane < partner) ? (val < p ? val : p) : (val > p ? val : p);
                    }
                }
                if (lane < deg) csr_edge[beg + lane] = val;
                // clamp sentinel lanes to a valid node id (aj stays 0 -> exact)
                sj = (lane < deg) ? (int)(unsigned)val : 0;
                aj = (lane < deg) ? __uint_as_float((unsigned)(val >> 32)) : 0.f;
                reg_path = true;
            } else if (deg > 64 && lane == 0) {
                for (int i = beg + 1; i < end; ++i) {
                    u64 key = csr_edge[i];
                    int j = i - 1;
                    while (j >= beg && csr_edge[j] > key) { csr_edge[j + 1] = csr_edge[j]; --j; }
                    csr_edge[j + 1] = key;
                }
            }
        }
        if (reg_path) {
            int npair = (deg + 1) >> 1;
            #pragma unroll 4
            for (int p = 0; p < npair; ++p) {
                int sel = 2 * p + half;
                int   s = __shfl(sj, sel);
                float a = __shfl(aj, sel);
                s16x8 v = *(const s16x8*)(hbf + (long)s * HDIM + col8);
                #pragma unroll
                for (int q = 0; q < 8; ++q)
                    acc[q] += a * bf2f((u16)v[q]);
            }
        } else {
            for (int c = beg; c < end; c += 64) {
                int m = end - c; if (m > 64) m = 64;
                u64 ej = csr_edge[c + (lane < m ? lane : 0)];
                int   sjc = (int)(unsigned)ej;
                float ajc = (lane < m) ? __uint_as_float((unsigned)(ej >> 32)) : 0.f;
                int npair = (m + 1) >> 1;
                #pragma unroll 4
                for (int p = 0; p < npair; ++p) {
                    int sel = 2 * p + half;
                    int   s = __shfl(sjc, sel);
                    float a = __shfl(ajc, sel);
                    s16x8 v = *(const s16x8*)(hbf + (long)s * HDIM + col8);
                    #pragma unroll
                    for (int q = 0; q < 8; ++q)
                        acc[q] += a * bf2f((u16)v[q]);
                }
            }
        }
    }
    #pragma unroll
    for (int q = 0; q < 8; ++q)
        acc[q] += __shfl_xor(acc[q], 32);
    if (half == 0) {
        s16x8 hv;
        #pragma unroll
        for (int q = 0; q < 8; ++q) hv[q] = (short)f2bf(acc[q]);
        *(s16x8*)(agg + (long)node * HDIM + col8) = hv;   // node<MPAD: pads get zeros
    }
}

// ---------------- GEMM: 64x128 tile, BK=64, gload_lds staging, swizzled LDS ----------------
// A bf16 [MPAD][256]; B pre-transposed bf16 [Nt][256].
// Row = 64 u16 = 128 B = 8 slots of 16 B. LDS[row][slot] = G[row][slot ^ (row&7)]
// via pre-swizzled global source; reads XOR the same way.
__global__ __launch_bounds__(256) void k_gemm(
    const u16* __restrict__ A1, const u16* __restrict__ A2,
    const u16* __restrict__ BT1, const u16* __restrict__ BT2,
    const float* __restrict__ bias,
    u16* __restrict__ hout, float* __restrict__ final_out, int Nt)
{
    __shared__ __align__(16) u16 As[64 * 64];    // 8 KB
    __shared__ __align__(16) u16 Bs[128 * 64];   // 16 KB

    const int t    = threadIdx.x;
    const int bm   = blockIdx.x, bn = blockIdx.y;
    const int lane = t & 63;
    const int wave = t >> 6;
    const int wr   = (wave >> 1) * 32;   // 0 | 32
    const int wc   = (wave & 1) * 64;    // 0 | 64
    const int lrow = lane & 15;
    const int lks  = lane >> 4;          // k-slot group 0..3

    f32x4 acc[2][4];
    #pragma unroll
    for (int i = 0; i < 2; ++i)
        #pragma unroll
        for (int j = 0; j < 4; ++j)
            #pragma unroll
            for (int r = 0; r < 4; ++r) acc[i][j][r] = 0.f;

    const int lrow8 = lane >> 3;
    const int ssrc  = ((lane & 7) ^ lrow8) * 8;   // u16 offset within row

    const int nmat = A2 ? 2 : 1;
    for (int mat = 0; mat < nmat; ++mat) {
        const u16* A_g = mat ? A2  : A1;
        const u16* B_g = mat ? BT2 : BT1;
        for (int k0 = 0; k0 < HDIM; k0 += 64) {
            __syncthreads();
            #pragma unroll
            for (int i = 0; i < 2; ++i) {
                int ch  = wave * 2 + i;
                int row = ch * 8 + lrow8;
                gload16(A_g + (size_t)(bm * 64 + row) * HDIM + k0 + ssrc, &As[ch * 512]);
            }
            #pragma unroll
            for (int i = 0; i < 4; ++i) {
                int ch  = wave * 4 + i;
                int row = ch * 8 + lrow8;
                gload16(B_g + (size_t)(bn * 128 + row) * HDIM + k0 + ssrc, &Bs[ch * 512]);
            }
            __syncthreads();
            #pragma unroll
            for (int kk = 0; kk < 2; ++kk) {
                int slot = kk * 4 + lks;
                s16x8 bfr[4];
                #pragma unroll
                for (int nj = 0; nj < 4; ++nj) {
                    int r = wc + nj * 16 + lrow;
                    bfr[nj] = *(const s16x8*)&Bs[r * 64 + ((slot ^ (r & 7)) * 8)];
                }
                #pragma unroll
                for (int mi = 0; mi < 2; ++mi) {
                    int r = wr + mi * 16 + lrow;
                    s16x8 a = *(const s16x8*)&As[r * 64 + ((slot ^ (r & 7)) * 8)];
                    #pragma unroll
                    for (int nj = 0; nj < 4; ++nj)
                        acc[mi][nj] = __builtin_amdgcn_mfma_f32_16x16x32_bf16(a, bfr[nj], acc[mi][nj], 0, 0, 0);
                }
            }
        }
    }

    const int rb = (lane >> 4) * 4;
    #pragma unroll
    for (int mi = 0; mi < 2; ++mi) {
        #pragma unroll
        for (int nj = 0; nj < 4; ++nj) {
            int col = bn * 128 + wc + nj * 16 + lrow;
            float bsv = bias[col];
            #pragma unroll
            for (int r = 0; r < 4; ++r) {
                int row = bm * 64 + wr + mi * 16 + rb + r;
                float v = acc[mi][nj][r] + bsv;
                v = v > 0.f ? v : 0.f;
                if (final_out) {
                    if (row < NREAL) final_out[(long)row * Nt + col] = v;
                } else {
                    hout[(long)row * HDIM + col] = f2bf(v);
                }
            }
        }
    }
}

static inline char* align256(char* p) {
    return (char*)(((size_t)p + 255) & ~(size_t)255);
}

extern "C" void kernel_launch(void* const* d_in, const int* in_sizes, int n_in,
                              void* d_out, int out_size, void* d_ws, size_t ws_size,
                              hipStream_t stream) {
    const float* x     = (const float*)d_in[0];
    const int*   eidx  = (const int*)  d_in[1];
    const float* attr  = (const float*)d_in[2];
    const float* wrel  = (const float*)d_in[3];
    const float* brel  = (const float*)d_in[4];
    const float* wroot = (const float*)d_in[5];
    const float* wout  = (const float*)d_in[6];
    const float* bout  = (const float*)d_in[7];
    const int* src = eidx;
    const int* dst = eidx + NEDGE;

    char* ws = (char*)d_ws;
    u16* hbfA  = (u16*)ws;        ws = align256(ws + (size_t)MPAD * HDIM * 2);
    u16* hbfB  = (u16*)ws;        ws = align256(ws + (size_t)MPAD * HDIM * 2);
    u16* aggbf = (u16*)ws;        ws = align256(ws + (size_t)MPAD * HDIM * 2);
    u16* brelT  = (u16*)ws;       ws = align256(ws + (size_t)3 * 65536 * 2);
    u16* brootT = (u16*)ws;       ws = align256(ws + (size_t)3 * 65536 * 2);
    u16* boutT  = (u16*)ws;       ws = align256(ws + (size_t)128 * 256 * 2);
    int* deg    = (int*)ws;       ws = align256(ws + (size_t)NREAL * 4);
    int* rowptr = (int*)ws;       ws = align256(ws + (size_t)(NREAL + 1) * 4);
    int* cursor = (int*)ws;       ws = align256(ws + (size_t)NREAL * 4);
    int* bsum   = (int*)ws;       ws = align256(ws + (size_t)SCAN_B * 4);
    int* boff   = (int*)ws;       ws = align256(ws + (size_t)SCAN_B * 4);
    u64* csr_edge = (u64*)ws;     ws = align256(ws + (size_t)NEDGE * 8);

    hipMemsetAsync(deg, 0, (size_t)NREAL * 4, stream);
    k_prep<<<2048, 256, 0, stream>>>(x, hbfA, wrel, wroot, wout,
                                     brelT, brootT, boutT, dst, deg);
    k_blocksum<<<SCAN_B, 1024, 0, stream>>>(deg, bsum);
    k_scansmall<<<1, 64, 0, stream>>>(bsum, boff);
    k_scanfinal<<<SCAN_B, 1024, 0, stream>>>(deg, boff, rowptr, cursor);
    k_fill<<<(NEDGE + 255) / 256, 256, 0, stream>>>(src, dst, attr, cursor, csr_edge);

    u16* h_c = hbfA;
    u16* h_n = hbfB;
    for (int l = 0; l < 3; ++l) {
        if (l == 0)
            k_aggregate<true><<<MPAD / 4, 256, 0, stream>>>(h_c, rowptr, csr_edge, aggbf);
        else
            k_aggregate<false><<<MPAD / 4, 256, 0, stream>>>(h_c, rowptr, csr_edge, aggbf);
        k_gemm<<<dim3(MPAD / 64, 2), 256, 0, stream>>>(
            aggbf, h_c,
            brelT + (size_t)l * 65536, brootT + (size_t)l * 65536,
            brel + (size_t)l * HDIM,
            h_n, nullptr, HDIM);
        u16* tp = h_c; h_c = h_n; h_n = tp;
    }
    k_gemm<<<dim3(MPAD / 64, 1), 256, 0, stream>>>(
        h_c, nullptr, boutT, nullptr, bout,
        nullptr, (float*)d_out, ODIM);
}

// Round 11
// 176.915 us; speedup vs baseline: 3.2014x; 1.0644x over previous
//
#include <hip/hip_runtime.h>

#define NREAL 20000
#define MPAD  20096      // 314 * 64
#define HDIM  256
#define ODIM  128
#define NEDGE 320000
#define SCAN_B 20        // ceil(NREAL/1024)

typedef __attribute__((ext_vector_type(4))) float f32x4;
typedef __attribute__((ext_vector_type(2))) float f32x2;
typedef __attribute__((ext_vector_type(8))) short s16x8;
typedef __attribute__((ext_vector_type(4))) unsigned short u16x4;
typedef unsigned short u16;
typedef unsigned int u32;

__device__ inline u16 f2bf(float f) {
    u32 u = __float_as_uint(f);
    return (u16)((u + 0x7FFFu + ((u >> 16) & 1u)) >> 16);
}
__device__ inline float bf2f(u16 s) { return __uint_as_float(((u32)s) << 16); }

__device__ __forceinline__ void gload16(const void* g, void* l) {
    __builtin_amdgcn_global_load_lds((const __attribute__((address_space(1))) void*)g,
                                     (__attribute__((address_space(3))) void*)l, 16, 0, 0);
}

// ---------------- prep: pad-convert x, weight transpose/convert, degree count ----------------
__global__ __launch_bounds__(256) void k_prep(
    const float* __restrict__ x, u16* __restrict__ hbf,
    const float* __restrict__ wrel, const float* __restrict__ wroot,
    const float* __restrict__ wout,
    u16* __restrict__ brelT, u16* __restrict__ brootT, u16* __restrict__ boutT,
    const int* __restrict__ dst, int* __restrict__ deg)
{
    const int gt = blockIdx.x * 256 + threadIdx.x;
    const int gsz = gridDim.x * 256;
    for (long gid = gt; gid < (long)MPAD * HDIM / 4; gid += gsz) {
        long base = gid * 4;
        long row  = base >> 8;
        f32x4 v = {0.f, 0.f, 0.f, 0.f};
        if (row < NREAL) v = *(const f32x4*)(x + base);
        u16x4 hv;
        for (int j = 0; j < 4; ++j) hv[j] = f2bf(v[j]);
        *(u16x4*)(hbf + base) = hv;
    }
    for (int i = gt; i < 3 * 65536; i += gsz) {
        int l = i >> 16, r = i & 65535, n = r >> 8, k = r & 255;
        brelT[i]  = f2bf(wrel [l * 65536 + k * 256 + n]);
        brootT[i] = f2bf(wroot[l * 65536 + k * 256 + n]);
    }
    for (int i = gt; i < 128 * 256; i += gsz) {
        int n = i >> 8, k = i & 255;
        boutT[i] = f2bf(wout[k * 128 + n]);
    }
    for (int e = gt; e < NEDGE; e += gsz) atomicAdd(&deg[dst[e]], 1);
}

// ---------------- scan chain ----------------
__global__ __launch_bounds__(1024) void k_blocksum(const int* __restrict__ deg,
                                                   int* __restrict__ bsum) {
    __shared__ int red[16];
    int b = blockIdx.x, t = threadIdx.x;
    int i = b * 1024 + t;
    int v = (i < NREAL) ? deg[i] : 0;
    for (int off = 32; off; off >>= 1) v += __shfl_down(v, off);
    if ((t & 63) == 0) red[t >> 6] = v;
    __syncthreads();
    if (t < 16) {
        int s = red[t];
        for (int off = 8; off; off >>= 1) s += __shfl_down(s, off);
        if (t == 0) bsum[b] = s;
    }
}

__global__ void k_scansmall(const int* __restrict__ bsum, int* __restrict__ boff) {
    int t = threadIdx.x;  // one wave
    int v = (t < SCAN_B) ? bsum[t] : 0;
    int orig = v;
    for (int off = 1; off < 64; off <<= 1) {
        int u = __shfl_up(v, off);
        if (t >= off) v += u;
    }
    if (t < SCAN_B) boff[t] = v - orig;
}

__global__ __launch_bounds__(1024) void k_scanfinal(const int* __restrict__ deg,
                                                    const int* __restrict__ boff,
                                                    int* __restrict__ rowptr,
                                                    int* __restrict__ cursor) {
    __shared__ int sm[1024];
    int b = blockIdx.x, t = threadIdx.x;
    int i = b * 1024 + t;
    int v = (i < NREAL) ? deg[i] : 0;
    sm[t] = v;
    __syncthreads();
    for (int off = 1; off < 1024; off <<= 1) {
        int u = (t >= off) ? sm[t - off] : 0;
        __syncthreads();
        if (t >= off) sm[t] += u;
        __syncthreads();
    }
    if (i < NREAL) {
        int excl = boff[b] + sm[t] - v;
        rowptr[i] = excl;
        cursor[i] = excl;
    }
    if (b == 0 && t == 0) rowptr[NREAL] = NEDGE;
}

// edge key: (attr_bf16 << 16) | src   (src < 2^16)
__global__ void k_fill(const int* __restrict__ src, const int* __restrict__ dst,
                       const float* __restrict__ attr, int* __restrict__ cursor,
                       u32* __restrict__ csr_edge) {
    int e = blockIdx.x * 256 + threadIdx.x;
    if (e < NEDGE) {
        int d = dst[e];
        int p = atomicAdd(&cursor[d], 1);
        csr_edge[p] = (((u32)f2bf(attr[e])) << 16) | (u32)src[e];
    }
}

// ---------------- aggregation: wave per node, 2 edges/iter, bf16 gather, pk-f32 math ----
// SORT=true (layer 1): canonically sort the segment in registers (odd-even net),
// write back for layers 2-3, aggregate from sorted registers -> all downstream fp
// order is a deterministic function of the inputs.
template <bool SORT>
__global__ __launch_bounds__(256) void k_aggregate(
    const u16* __restrict__ hbf, const int* __restrict__ rowptr,
    u32* __restrict__ csr_edge, u16* __restrict__ agg)
{
    const int node = blockIdx.x * 4 + (threadIdx.x >> 6);
    const int lane = threadIdx.x & 63;
    const int half = lane >> 5;
    const int col8 = (lane & 31) * 8;
    f32x2 acc2[4];
    #pragma unroll
    for (int k = 0; k < 4; ++k) { acc2[k][0] = 0.f; acc2[k][1] = 0.f; }

    if (node < NREAL) {
        const int beg = rowptr[node], end = rowptr[node + 1];
        const int deg = end - beg;
        bool reg_path = false;
        u32 ej = 0;
        if (SORT) {
            if (deg >= 1 && deg <= 64) {
                u32 val = (lane < deg) ? csr_edge[beg + lane] : 0xFFFFFFFFu;
                if (deg > 1) {
                    #pragma unroll
                    for (int ph = 0; ph < 64; ++ph) {
                        int base = ph & 1;
                        int partner = lane + (((lane ^ base) & 1) ? -1 : +1);
                        if (partner < 0 || partner > 63) partner = lane;
                        u32 p = (u32)__shfl((int)val, partner);
                        if (partner != lane)
                            val = (lane < partner) ? (val < p ? val : p) : (val > p ? val : p);
                    }
                }
                if (lane < deg) csr_edge[beg + lane] = val;
                ej = (lane < deg) ? val : 0u;   // attr=0, src=0 for pad lanes
                reg_path = true;
            } else if (deg > 64 && lane == 0) {
                for (int i = beg + 1; i < end; ++i) {
                    u32 key = csr_edge[i];
                    int j = i - 1;
                    while (j >= beg && csr_edge[j] > key) { csr_edge[j + 1] = csr_edge[j]; --j; }
                    csr_edge[j + 1] = key;
                }
            }
        }
        if (reg_path) {
            int npair = (deg + 1) >> 1;
            #pragma unroll 4
            for (int p = 0; p < npair; ++p) {
                u32 e = (u32)__shfl((int)ej, 2 * p + half);
                float a = __uint_as_float(e & 0xffff0000u);
                f32x2 a2 = {a, a};
                s16x8 v = *(const s16x8*)(hbf + ((long)(e & 0xffffu) << 8) + col8);
                const u32* vw = (const u32*)&v;
                #pragma unroll
                for (int k = 0; k < 4; ++k) {
                    f32x2 hv = {__uint_as_float(vw[k] << 16),
                                __uint_as_float(vw[k] & 0xffff0000u)};
                    acc2[k] += a2 * hv;
                }
            }
        } else {
            for (int c = beg; c < end; c += 64) {
                int m = end - c; if (m > 64) m = 64;
                u32 ejc = csr_edge[c + (lane < m ? lane : 0)];
                if (lane >= m) ejc = 0u;
                int npair = (m + 1) >> 1;
                #pragma unroll 4
                for (int p = 0; p < npair; ++p) {
                    u32 e = (u32)__shfl((int)ejc, 2 * p + half);
                    float a = __uint_as_float(e & 0xffff0000u);
                    f32x2 a2 = {a, a};
                    s16x8 v = *(const s16x8*)(hbf + ((long)(e & 0xffffu) << 8) + col8);
                    const u32* vw = (const u32*)&v;
                    #pragma unroll
                    for (int k = 0; k < 4; ++k) {
                        f32x2 hv = {__uint_as_float(vw[k] << 16),
                                    __uint_as_float(vw[k] & 0xffff0000u)};
                        acc2[k] += a2 * hv;
                    }
                }
            }
        }
    }
    #pragma unroll
    for (int k = 0; k < 4; ++k) {
        acc2[k][0] += __shfl_xor(acc2[k][0], 32);
        acc2[k][1] += __shfl_xor(acc2[k][1], 32);
    }
    if (half == 0) {
        s16x8 hv;
        #pragma unroll
        for (int k = 0; k < 4; ++k) {
            hv[2 * k]     = (short)f2bf(acc2[k][0]);
            hv[2 * k + 1] = (short)f2bf(acc2[k][1]);
        }
        *(s16x8*)(agg + (long)node * HDIM + col8) = hv;   // pads get zeros
    }
}

// ---------------- GEMM: 64x128 tile, BK=64, gload_lds staging, swizzled LDS ----------------
// A bf16 [MPAD][256]; B pre-transposed bf16 [Nt][256].
// Row = 64 u16 = 8 slots of 16 B. LDS[row][slot] = G[row][slot ^ (row&7)]
// via pre-swizzled global source; reads XOR the same way.
__global__ __launch_bounds__(256) void k_gemm(
    const u16* __restrict__ A1, const u16* __restrict__ A2,
    const u16* __restrict__ BT1, const u16* __restrict__ BT2,
    const float* __restrict__ bias,
    u16* __restrict__ hout, float* __restrict__ final_out, int Nt)
{
    __shared__ __align__(16) u16 As[64 * 64];    // 8 KB
    __shared__ __align__(16) u16 Bs[128 * 64];   // 16 KB

    const int t    = threadIdx.x;
    const int bm   = blockIdx.x, bn = blockIdx.y;
    const int lane = t & 63;
    const int wave = t >> 6;
    const int wr   = (wave >> 1) * 32;   // 0 | 32
    const int wc   = (wave & 1) * 64;    // 0 | 64
    const int lrow = lane & 15;
    const int lks  = lane >> 4;          // k-slot group 0..3

    f32x4 acc[2][4];
    #pragma unroll
    for (int i = 0; i < 2; ++i)
        #pragma unroll
        for (int j = 0; j < 4; ++j)
            #pragma unroll
            for (int r = 0; r < 4; ++r) acc[i][j][r] = 0.f;

    const int lrow8 = lane >> 3;
    const int ssrc  = ((lane & 7) ^ lrow8) * 8;   // u16 offset within row

    const int nmat = A2 ? 2 : 1;
    for (int mat = 0; mat < nmat; ++mat) {
        const u16* A_g = mat ? A2  : A1;
        const u16* B_g = mat ? BT2 : BT1;
        for (int k0 = 0; k0 < HDIM; k0 += 64) {
            __syncthreads();
            #pragma unroll
            for (int i = 0; i < 2; ++i) {
                int ch  = wave * 2 + i;
                int row = ch * 8 + lrow8;
                gload16(A_g + (size_t)(bm * 64 + row) * HDIM + k0 + ssrc, &As[ch * 512]);
            }
            #pragma unroll
            for (int i = 0; i < 4; ++i) {
                int ch  = wave * 4 + i;
                int row = ch * 8 + lrow8;
                gload16(B_g + (size_t)(bn * 128 + row) * HDIM + k0 + ssrc, &Bs[ch * 512]);
            }
            __syncthreads();
            #pragma unroll
            for (int kk = 0; kk < 2; ++kk) {
                int slot = kk * 4 + lks;
                s16x8 bfr[4];
                #pragma unroll
                for (int nj = 0; nj < 4; ++nj) {
                    int r = wc + nj * 16 + lrow;
                    bfr[nj] = *(const s16x8*)&Bs[r * 64 + ((slot ^ (r & 7)) * 8)];
                }
                #pragma unroll
                for (int mi = 0; mi < 2; ++mi) {
                    int r = wr + mi * 16 + lrow;
                    s16x8 a = *(const s16x8*)&As[r * 64 + ((slot ^ (r & 7)) * 8)];
                    #pragma unroll
                    for (int nj = 0; nj < 4; ++nj)
                        acc[mi][nj] = __builtin_amdgcn_mfma_f32_16x16x32_bf16(a, bfr[nj], acc[mi][nj], 0, 0, 0);
                }
            }
        }
    }

    const int rb = (lane >> 4) * 4;
    #pragma unroll
    for (int mi = 0; mi < 2; ++mi) {
        #pragma unroll
        for (int nj = 0; nj < 4; ++nj) {
            int col = bn * 128 + wc + nj * 16 + lrow;
            float bsv = bias[col];
            #pragma unroll
            for (int r = 0; r < 4; ++r) {
                int row = bm * 64 + wr + mi * 16 + rb + r;
                float v = acc[mi][nj][r] + bsv;
                v = v > 0.f ? v : 0.f;
                if (final_out) {
                    if (row < NREAL) final_out[(long)row * Nt + col] = v;
                } else {
                    hout[(long)row * HDIM + col] = f2bf(v);
                }
            }
        }
    }
}

static inline char* align256(char* p) {
    return (char*)(((size_t)p + 255) & ~(size_t)255);
}

extern "C" void kernel_launch(void* const* d_in, const int* in_sizes, int n_in,
                              void* d_out, int out_size, void* d_ws, size_t ws_size,
                              hipStream_t stream) {
    const float* x     = (const float*)d_in[0];
    const int*   eidx  = (const int*)  d_in[1];
    const float* attr  = (const float*)d_in[2];
    const float* wrel  = (const float*)d_in[3];
    const float* brel  = (const float*)d_in[4];
    const float* wroot = (const float*)d_in[5];
    const float* wout  = (const float*)d_in[6];
    const float* bout  = (const float*)d_in[7];
    const int* src = eidx;
    const int* dst = eidx + NEDGE;

    char* ws = (char*)d_ws;
    u16* hbfA  = (u16*)ws;        ws = align256(ws + (size_t)MPAD * HDIM * 2);
    u16* hbfB  = (u16*)ws;        ws = align256(ws + (size_t)MPAD * HDIM * 2);
    u16* aggbf = (u16*)ws;        ws = align256(ws + (size_t)MPAD * HDIM * 2);
    u16* brelT  = (u16*)ws;       ws = align256(ws + (size_t)3 * 65536 * 2);
    u16* brootT = (u16*)ws;       ws = align256(ws + (size_t)3 * 65536 * 2);
    u16* boutT  = (u16*)ws;       ws = align256(ws + (size_t)128 * 256 * 2);
    int* deg    = (int*)ws;       ws = align256(ws + (size_t)NREAL * 4);
    int* rowptr = (int*)ws;       ws = align256(ws + (size_t)(NREAL + 1) * 4);
    int* cursor = (int*)ws;       ws = align256(ws + (size_t)NREAL * 4);
    int* bsum   = (int*)ws;       ws = align256(ws + (size_t)SCAN_B * 4);
    int* boff   = (int*)ws;       ws = align256(ws + (size_t)SCAN_B * 4);
    u32* csr_edge = (u32*)ws;     ws = align256(ws + (size_t)NEDGE * 4);

    hipMemsetAsync(deg, 0, (size_t)NREAL * 4, stream);
    k_prep<<<2048, 256, 0, stream>>>(x, hbfA, wrel, wroot, wout,
                                     brelT, brootT, boutT, dst, deg);
    k_blocksum<<<SCAN_B, 1024, 0, stream>>>(deg, bsum);
    k_scansmall<<<1, 64, 0, stream>>>(bsum, boff);
    k_scanfinal<<<SCAN_B, 1024, 0, stream>>>(deg, boff, rowptr, cursor);
    k_fill<<<(NEDGE + 255) / 256, 256, 0, stream>>>(src, dst, attr, cursor, csr_edge);

    u16* h_c = hbfA;
    u16* h_n = hbfB;
    for (int l = 0; l < 3; ++l) {
        if (l == 0)
            k_aggregate<true><<<MPAD / 4, 256, 0, stream>>>(h_c, rowptr, csr_edge, aggbf);
        else
            k_aggregate<false><<<MPAD / 4, 256, 0, stream>>>(h_c, rowptr, csr_edge, aggbf);
        k_gemm<<<dim3(MPAD / 64, 2), 256, 0, stream>>>(
            aggbf, h_c,
            brelT + (size_t)l * 65536, brootT + (size_t)l * 65536,
            brel + (size_t)l * HDIM,
            h_n, nullptr, HDIM);
        u16* tp = h_c; h_c = h_n; h_n = tp;
    }
    k_gemm<<<dim3(MPAD / 64, 1), 256, 0, stream>>>(
        h_c, nullptr, boutT, nullptr, bout,
        nullptr, (float*)d_out, ODIM);
}

// Round 12
// 169.460 us; speedup vs baseline: 3.3423x; 1.0440x over previous
//
#include <hip/hip_runtime.h>

#define NREAL 20000
#define MPAD  20096      // 314 * 64
#define HDIM  256
#define ODIM  128
#define NEDGE 320000
#define SCAN_B 20        // ceil(NREAL/1024)

typedef __attribute__((ext_vector_type(4))) float f32x4;
typedef __attribute__((ext_vector_type(2))) float f32x2;
typedef __attribute__((ext_vector_type(8))) short s16x8;
typedef __attribute__((ext_vector_type(4))) unsigned short u16x4;
typedef unsigned short u16;
typedef unsigned int u32;

__device__ inline u16 f2bf(float f) {
    u32 u = __float_as_uint(f);
    return (u16)((u + 0x7FFFu + ((u >> 16) & 1u)) >> 16);
}
__device__ inline float bf2f(u16 s) { return __uint_as_float(((u32)s) << 16); }

__device__ __forceinline__ void gload16(const void* g, void* l) {
    __builtin_amdgcn_global_load_lds((const __attribute__((address_space(1))) void*)g,
                                     (__attribute__((address_space(3))) void*)l, 16, 0, 0);
}

// ---------------- prep: pad-convert x, weight transpose/convert, degree count ----------------
__global__ __launch_bounds__(256) void k_prep(
    const float* __restrict__ x, u16* __restrict__ hbf,
    const float* __restrict__ wrel, const float* __restrict__ wroot,
    const float* __restrict__ wout,
    u16* __restrict__ brelT, u16* __restrict__ brootT, u16* __restrict__ boutT,
    const int* __restrict__ dst, int* __restrict__ deg)
{
    const int gt = blockIdx.x * 256 + threadIdx.x;
    const int gsz = gridDim.x * 256;
    for (long gid = gt; gid < (long)MPAD * HDIM / 4; gid += gsz) {
        long base = gid * 4;
        long row  = base >> 8;
        f32x4 v = {0.f, 0.f, 0.f, 0.f};
        if (row < NREAL) v = *(const f32x4*)(x + base);
        u16x4 hv;
        for (int j = 0; j < 4; ++j) hv[j] = f2bf(v[j]);
        *(u16x4*)(hbf + base) = hv;
    }
    for (int i = gt; i < 3 * 65536; i += gsz) {
        int l = i >> 16, r = i & 65535, n = r >> 8, k = r & 255;
        brelT[i]  = f2bf(wrel [l * 65536 + k * 256 + n]);
        brootT[i] = f2bf(wroot[l * 65536 + k * 256 + n]);
    }
    for (int i = gt; i < 128 * 256; i += gsz) {
        int n = i >> 8, k = i & 255;
        boutT[i] = f2bf(wout[k * 128 + n]);
    }
    for (int e = gt; e < NEDGE; e += gsz) atomicAdd(&deg[dst[e]], 1);
}

// ---------------- scan chain ----------------
__global__ __launch_bounds__(1024) void k_blocksum(const int* __restrict__ deg,
                                                   int* __restrict__ bsum) {
    __shared__ int red[16];
    int b = blockIdx.x, t = threadIdx.x;
    int i = b * 1024 + t;
    int v = (i < NREAL) ? deg[i] : 0;
    for (int off = 32; off; off >>= 1) v += __shfl_down(v, off);
    if ((t & 63) == 0) red[t >> 6] = v;
    __syncthreads();
    if (t < 16) {
        int s = red[t];
        for (int off = 8; off; off >>= 1) s += __shfl_down(s, off);
        if (t == 0) bsum[b] = s;
    }
}

__global__ void k_scansmall(const int* __restrict__ bsum, int* __restrict__ boff) {
    int t = threadIdx.x;  // one wave
    int v = (t < SCAN_B) ? bsum[t] : 0;
    int orig = v;
    for (int off = 1; off < 64; off <<= 1) {
        int u = __shfl_up(v, off);
        if (t >= off) v += u;
    }
    if (t < SCAN_B) boff[t] = v - orig;
}

__global__ __launch_bounds__(1024) void k_scanfinal(const int* __restrict__ deg,
                                                    const int* __restrict__ boff,
                                                    int* __restrict__ rowptr,
                                                    int* __restrict__ cursor) {
    __shared__ int sm[1024];
    int b = blockIdx.x, t = threadIdx.x;
    int i = b * 1024 + t;
    int v = (i < NREAL) ? deg[i] : 0;
    sm[t] = v;
    __syncthreads();
    for (int off = 1; off < 1024; off <<= 1) {
        int u = (t >= off) ? sm[t - off] : 0;
        __syncthreads();
        if (t >= off) sm[t] += u;
        __syncthreads();
    }
    if (i < NREAL) {
        int excl = boff[b] + sm[t] - v;
        rowptr[i] = excl;
        cursor[i] = excl;
    }
    if (b == 0 && t == 0) rowptr[NREAL] = NEDGE;
}

// edge key: (attr_bf16 << 16) | src   (src < 2^16)
__global__ void k_fill(const int* __restrict__ src, const int* __restrict__ dst,
                       const float* __restrict__ attr, int* __restrict__ cursor,
                       u32* __restrict__ csr_edge) {
    int e = blockIdx.x * 256 + threadIdx.x;
    if (e < NEDGE) {
        int d = dst[e];
        int p = atomicAdd(&cursor[d], 1);
        csr_edge[p] = (((u32)f2bf(attr[e])) << 16) | (u32)src[e];
    }
}

// 8-deep pipelined gather-accumulate over one zero-padded 64-edge chunk.
// ej: per-lane meta (attr<<16|src), zero for pad lanes; npair <= 32.
__device__ __forceinline__ void agg_pairs(u32 ej, int npair, int half, int col8,
                                          const u16* __restrict__ hbf, f32x2 acc2[4]) {
    const int nbat = (npair + 7) >> 3;
    for (int bt = 0; bt < nbat; ++bt) {
        u32 ee[8];
        s16x8 v[8];
        #pragma unroll
        for (int b = 0; b < 8; ++b) {
            ee[b] = (u32)__shfl((int)ej, 2 * (bt * 8 + b) + half);   // <= 63
            v[b]  = *(const s16x8*)(hbf + ((long)(ee[b] & 0xffffu) << 8) + col8);
        }
        #pragma unroll
        for (int b = 0; b < 8; ++b) {
            float a = __uint_as_float(ee[b] & 0xffff0000u);
            f32x2 a2 = {a, a};
            const u32* vw = (const u32*)&v[b];
            #pragma unroll
            for (int k = 0; k < 4; ++k) {
                f32x2 hv = {__uint_as_float(vw[k] << 16),
                            __uint_as_float(vw[k] & 0xffff0000u)};
                acc2[k] += a2 * hv;
            }
        }
    }
}

// ---------------- aggregation: wave per node, 8-deep gather pipeline ----------------
// SORT=true (layer 1): canonically sort the segment in registers (odd-even net),
// write back for layers 2-3 -> downstream fp order deterministic.
template <bool SORT>
__global__ __launch_bounds__(256) void k_aggregate(
    const u16* __restrict__ hbf, const int* __restrict__ rowptr,
    u32* __restrict__ csr_edge, u16* __restrict__ agg)
{
    const int node = blockIdx.x * 4 + (threadIdx.x >> 6);
    const int lane = threadIdx.x & 63;
    const int half = lane >> 5;
    const int col8 = (lane & 31) * 8;
    f32x2 acc2[4];
    #pragma unroll
    for (int k = 0; k < 4; ++k) { acc2[k][0] = 0.f; acc2[k][1] = 0.f; }

    if (node < NREAL) {
        const int beg = rowptr[node], end = rowptr[node + 1];
        const int deg = end - beg;
        bool reg_path = false;
        u32 ej = 0;
        if (SORT) {
            if (deg >= 1 && deg <= 64) {
                u32 val = (lane < deg) ? csr_edge[beg + lane] : 0xFFFFFFFFu;
                if (deg > 1) {
                    #pragma unroll
                    for (int ph = 0; ph < 64; ++ph) {
                        int base = ph & 1;
                        int partner = lane + (((lane ^ base) & 1) ? -1 : +1);
                        if (partner < 0 || partner > 63) partner = lane;
                        u32 p = (u32)__shfl((int)val, partner);
                        if (partner != lane)
                            val = (lane < partner) ? (val < p ? val : p) : (val > p ? val : p);
                    }
                }
                if (lane < deg) csr_edge[beg + lane] = val;
                ej = (lane < deg) ? val : 0u;   // pad lanes: attr=0, src=0
                reg_path = true;
            } else if (deg > 64 && lane == 0) {
                for (int i = beg + 1; i < end; ++i) {
                    u32 key = csr_edge[i];
                    int j = i - 1;
                    while (j >= beg && csr_edge[j] > key) { csr_edge[j + 1] = csr_edge[j]; --j; }
                    csr_edge[j + 1] = key;
                }
            }
        }
        if (reg_path) {
            agg_pairs(ej, (deg + 1) >> 1, half, col8, hbf, acc2);
        } else {
            for (int c = beg; c < end; c += 64) {
                int m = end - c; if (m > 64) m = 64;
                u32 ejc = csr_edge[c + (lane < m ? lane : 0)];
                if (lane >= m) ejc = 0u;
                agg_pairs(ejc, (m + 1) >> 1, half, col8, hbf, acc2);
            }
        }
    }
    #pragma unroll
    for (int k = 0; k < 4; ++k) {
        acc2[k][0] += __shfl_xor(acc2[k][0], 32);
        acc2[k][1] += __shfl_xor(acc2[k][1], 32);
    }
    if (half == 0) {
        s16x8 hv;
        #pragma unroll
        for (int k = 0; k < 4; ++k) {
            hv[2 * k]     = (short)f2bf(acc2[k][0]);
            hv[2 * k + 1] = (short)f2bf(acc2[k][1]);
        }
        *(s16x8*)(agg + (long)node * HDIM + col8) = hv;   // pads get zeros
    }
}

// ---------------- GEMM: 64x128 tile, BK=64, gload_lds staging, swizzled LDS ----------------
// A bf16 [MPAD][256]; B pre-transposed bf16 [Nt][256].
// Row = 64 u16 = 8 slots of 16 B. LDS[row][slot] = G[row][slot ^ (row&7)]
// via pre-swizzled global source; reads XOR the same way.
__global__ __launch_bounds__(256) void k_gemm(
    const u16* __restrict__ A1, const u16* __restrict__ A2,
    const u16* __restrict__ BT1, const u16* __restrict__ BT2,
    const float* __restrict__ bias,
    u16* __restrict__ hout, float* __restrict__ final_out, int Nt)
{
    __shared__ __align__(16) u16 As[64 * 64];    // 8 KB
    __shared__ __align__(16) u16 Bs[128 * 64];   // 16 KB

    const int t    = threadIdx.x;
    const int bm   = blockIdx.x, bn = blockIdx.y;
    const int lane = t & 63;
    const int wave = t >> 6;
    const int wr   = (wave >> 1) * 32;   // 0 | 32
    const int wc   = (wave & 1) * 64;    // 0 | 64
    const int lrow = lane & 15;
    const int lks  = lane >> 4;          // k-slot group 0..3

    f32x4 acc[2][4];
    #pragma unroll
    for (int i = 0; i < 2; ++i)
        #pragma unroll
        for (int j = 0; j < 4; ++j)
            #pragma unroll
            for (int r = 0; r < 4; ++r) acc[i][j][r] = 0.f;

    const int lrow8 = lane >> 3;
    const int ssrc  = ((lane & 7) ^ lrow8) * 8;   // u16 offset within row

    const int nmat = A2 ? 2 : 1;
    for (int mat = 0; mat < nmat; ++mat) {
        const u16* A_g = mat ? A2  : A1;
        const u16* B_g = mat ? BT2 : BT1;
        for (int k0 = 0; k0 < HDIM; k0 += 64) {
            __syncthreads();
            #pragma unroll
            for (int i = 0; i < 2; ++i) {
                int ch  = wave * 2 + i;
                int row = ch * 8 + lrow8;
                gload16(A_g + (size_t)(bm * 64 + row) * HDIM + k0 + ssrc, &As[ch * 512]);
            }
            #pragma unroll
            for (int i = 0; i < 4; ++i) {
                int ch  = wave * 4 + i;
                int row = ch * 8 + lrow8;
                gload16(B_g + (size_t)(bn * 128 + row) * HDIM + k0 + ssrc, &Bs[ch * 512]);
            }
            __syncthreads();
            #pragma unroll
            for (int kk = 0; kk < 2; ++kk) {
                int slot = kk * 4 + lks;
                s16x8 bfr[4];
                #pragma unroll
                for (int nj = 0; nj < 4; ++nj) {
                    int r = wc + nj * 16 + lrow;
                    bfr[nj] = *(const s16x8*)&Bs[r * 64 + ((slot ^ (r & 7)) * 8)];
                }
                #pragma unroll
                for (int mi = 0; mi < 2; ++mi) {
                    int r = wr + mi * 16 + lrow;
                    s16x8 a = *(const s16x8*)&As[r * 64 + ((slot ^ (r & 7)) * 8)];
                    #pragma unroll
                    for (int nj = 0; nj < 4; ++nj)
                        acc[mi][nj] = __builtin_amdgcn_mfma_f32_16x16x32_bf16(a, bfr[nj], acc[mi][nj], 0, 0, 0);
                }
            }
        }
    }

    const int rb = (lane >> 4) * 4;
    #pragma unroll
    for (int mi = 0; mi < 2; ++mi) {
        #pragma unroll
        for (int nj = 0; nj < 4; ++nj) {
            int col = bn * 128 + wc + nj * 16 + lrow;
            float bsv = bias[col];
            #pragma unroll
            for (int r = 0; r < 4; ++r) {
                int row = bm * 64 + wr + mi * 16 + rb + r;
                float v = acc[mi][nj][r] + bsv;
                v = v > 0.f ? v : 0.f;
                if (final_out) {
                    if (row < NREAL) final_out[(long)row * Nt + col] = v;
                } else {
                    hout[(long)row * HDIM + col] = f2bf(v);
                }
            }
        }
    }
}

static inline char* align256(char* p) {
    return (char*)(((size_t)p + 255) & ~(size_t)255);
}

extern "C" void kernel_launch(void* const* d_in, const int* in_sizes, int n_in,
                              void* d_out, int out_size, void* d_ws, size_t ws_size,
                              hipStream_t stream) {
    const float* x     = (const float*)d_in[0];
    const int*   eidx  = (const int*)  d_in[1];
    const float* attr  = (const float*)d_in[2];
    const float* wrel  = (const float*)d_in[3];
    const float* brel  = (const float*)d_in[4];
    const float* wroot = (const float*)d_in[5];
    const float* wout  = (const float*)d_in[6];
    const float* bout  = (const float*)d_in[7];
    const int* src = eidx;
    const int* dst = eidx + NEDGE;

    char* ws = (char*)d_ws;
    u16* hbfA  = (u16*)ws;        ws = align256(ws + (size_t)MPAD * HDIM * 2);
    u16* hbfB  = (u16*)ws;        ws = align256(ws + (size_t)MPAD * HDIM * 2);
    u16* aggbf = (u16*)ws;        ws = align256(ws + (size_t)MPAD * HDIM * 2);
    u16* brelT  = (u16*)ws;       ws = align256(ws + (size_t)3 * 65536 * 2);
    u16* brootT = (u16*)ws;       ws = align256(ws + (size_t)3 * 65536 * 2);
    u16* boutT  = (u16*)ws;       ws = align256(ws + (size_t)128 * 256 * 2);
    int* deg    = (int*)ws;       ws = align256(ws + (size_t)NREAL * 4);
    int* rowptr = (int*)ws;       ws = align256(ws + (size_t)(NREAL + 1) * 4);
    int* cursor = (int*)ws;       ws = align256(ws + (size_t)NREAL * 4);
    int* bsum   = (int*)ws;       ws = align256(ws + (size_t)SCAN_B * 4);
    int* boff   = (int*)ws;       ws = align256(ws + (size_t)SCAN_B * 4);
    u32* csr_edge = (u32*)ws;     ws = align256(ws + (size_t)NEDGE * 4);

    hipMemsetAsync(deg, 0, (size_t)NREAL * 4, stream);
    k_prep<<<2048, 256, 0, stream>>>(x, hbfA, wrel, wroot, wout,
                                     brelT, brootT, boutT, dst, deg);
    k_blocksum<<<SCAN_B, 1024, 0, stream>>>(deg, bsum);
    k_scansmall<<<1, 64, 0, stream>>>(bsum, boff);
    k_scanfinal<<<SCAN_B, 1024, 0, stream>>>(deg, boff, rowptr, cursor);
    k_fill<<<(NEDGE + 255) / 256, 256, 0, stream>>>(src, dst, attr, cursor, csr_edge);

    u16* h_c = hbfA;
    u16* h_n = hbfB;
    for (int l = 0; l < 3; ++l) {
        if (l == 0)
            k_aggregate<true><<<MPAD / 4, 256, 0, stream>>>(h_c, rowptr, csr_edge, aggbf);
        else
            k_aggregate<false><<<MPAD / 4, 256, 0, stream>>>(h_c, rowptr, csr_edge, aggbf);
        k_gemm<<<dim3(MPAD / 64, 2), 256, 0, stream>>>(
            aggbf, h_c,
            brelT + (size_t)l * 65536, brootT + (size_t)l * 65536,
            brel + (size_t)l * HDIM,
            h_n, nullptr, HDIM);
        u16* tp = h_c; h_c = h_n; h_n = tp;
    }
    k_gemm<<<dim3(MPAD / 64, 1), 256, 0, stream>>>(
        h_c, nullptr, boutT, nullptr, bout,
        nullptr, (float*)d_out, ODIM);
}